// Round 15
// baseline (138.320 us; speedup 1.0000x reference)
//
#include <hip/hip_runtime.h>
#include <hip/hip_bf16.h>

#define ALPHA  0.2f
#define L2E    1.4426950408889634f

typedef __attribute__((ext_vector_type(8))) short  short8;
typedef __attribute__((ext_vector_type(4))) float  f32x4;
typedef unsigned short u16;

__device__ __forceinline__ u16 f2bf(float f) {
    union { __hip_bfloat16 h; u16 u; } v;
    v.h = __float2bfloat16(f);
    return v.u;
}
__device__ __forceinline__ unsigned pk2(float a, float b) {   // lo=a, hi=b
    union { __hip_bfloat162 h2; unsigned u; } v;
    float2 f2; f2.x = a; f2.y = b;
    v.h2 = __float22bfloat162_rn(f2);
    return v.u;
}
__device__ __forceinline__ float lrelu(float x) { return fmaxf(x, ALPHA * x); }

// ---- prep: W -> wfrag[pair 128][lane 64][8] (B-fragment-contiguous bf16),
//      pair = ks*16 + cblock; also w1 = W@a1, w2 = W@a2.
__global__ void prep(const float* __restrict__ W, const float* __restrict__ a1,
                     const float* __restrict__ a2, u16* __restrict__ wfrag,
                     float* __restrict__ w1, float* __restrict__ w2) {
    int b = blockIdx.x;
    if (b < 64) {
        int t    = threadIdx.x;
        int pair = b * 2 + (t >> 7);
        int l    = (t >> 1) & 63;
        int jh   = (t & 1) * 4;
        int ks   = pair >> 4, cb = pair & 15;
        int c  = cb * 16 + (l & 15);
        int k0 = ks * 32 + (l >> 4) * 8 + jh;
        ushort4 o;
        o.x = f2bf(W[(size_t)(k0 + 0) * 256 + c]);
        o.y = f2bf(W[(size_t)(k0 + 1) * 256 + c]);
        o.z = f2bf(W[(size_t)(k0 + 2) * 256 + c]);
        o.w = f2bf(W[(size_t)(k0 + 3) * 256 + c]);
        *(ushort4*)&wfrag[(size_t)pair * 512 + l * 8 + jh] = o;
    } else {
        int bb = b - 64;                       // 0..3
        int wv = threadIdx.x >> 6, lane = threadIdx.x & 63;
        for (int kk = 0; kk < 16; ++kk) {
            int k = bb * 64 + wv * 16 + kk;
            float4 wv4 = *(const float4*)(W + (size_t)k * 256 + 4 * lane);
            float4 a14 = *(const float4*)(a1 + 4 * lane);
            float4 a24 = *(const float4*)(a2 + 4 * lane);
            float d1 = wv4.x*a14.x + wv4.y*a14.y + wv4.z*a14.z + wv4.w*a14.w;
            float d2 = wv4.x*a24.x + wv4.y*a24.y + wv4.z*a24.z + wv4.w*a24.w;
            #pragma unroll
            for (int off = 32; off; off >>= 1) {
                d1 += __shfl_xor(d1, off);
                d2 += __shfl_xor(d2, off);
            }
            if (lane == 0) { w1[k] = d1; w2[k] = d2; }
        }
    }
}

// ===== fused kernel, cumulative-phase template for ablation ================
// P=1: Phase A only.  P=2: +GEMM1.  P=3: +transpose.  P=4: full (writes out).
// Structure = R12 (passing) with R11's 2-row Phase A (no spill).
template<int P>
__global__ __launch_bounds__(1024)
void gat(const int* __restrict__ item_seq, const float* __restrict__ emb,
         const float* __restrict__ pos, const float* __restrict__ gamma,
         const float* __restrict__ beta, const float* __restrict__ w1,
         const float* __restrict__ w2, const u16* __restrict__ wfrag,
         float* __restrict__ out, float* __restrict__ dummy)
{
    __shared__ u16 xb[256 * 256];            // 128 KB
    __shared__ __align__(16) float s1s[256], s2s[256];
    __shared__ float wmax[16];
    __shared__ float s2r;
    const int b    = blockIdx.x;
    const int tid  = threadIdx.x;
    const int lane = tid & 63, wid = tid >> 6, g = lane >> 4, li = lane & 15;
    const int iw_  = wid >> 2, nw = wid & 3;   // 4x4 wave grid (GEMM1)

    // ---- Phase A: gather + LN + s1/s2 (wave-per-row, 2 rows per iter) -----
    {
        float4 g4  = *(const float4*)(gamma + 4 * lane);
        float4 b4  = *(const float4*)(beta  + 4 * lane);
        float4 w14 = *(const float4*)(w1    + 4 * lane);
        float4 w24 = *(const float4*)(w2    + 4 * lane);
        float4 u4, t4;
        u4.x = g4.x*w14.x; u4.y = g4.y*w14.y; u4.z = g4.z*w14.z; u4.w = g4.w*w14.w;
        t4.x = g4.x*w24.x; t4.y = g4.y*w24.y; t4.z = g4.z*w24.z; t4.w = g4.w*w24.w;
        float cA = u4.x + u4.y + u4.z + u4.w;
        float cB = t4.x + t4.y + t4.z + t4.w;
        float cC = b4.x*w14.x + b4.y*w14.y + b4.z*w14.z + b4.w*w14.w;
        float cD = b4.x*w24.x + b4.y*w24.y + b4.z*w24.z + b4.w*w24.w;
        #pragma unroll
        for (int off = 32; off; off >>= 1) {
            cA += __shfl_xor(cA, off); cB += __shfl_xor(cB, off);
            cC += __shfl_xor(cC, off); cD += __shfl_xor(cD, off);
        }
        float rm = -3.0e38f;
        #pragma unroll 2
        for (int it = 0; it < 8; ++it) {
            int rA = it * 32 + wid, rB = rA + 16;
            int gA = item_seq[b * 256 + rA];
            int gB = item_seq[b * 256 + rB];
            float4 eA = *(const float4*)(emb + (size_t)gA * 256 + 4 * lane);
            float4 pA = *(const float4*)(pos + (size_t)rA * 256 + 4 * lane);
            float4 eB = *(const float4*)(emb + (size_t)gB * 256 + 4 * lane);
            float4 pB = *(const float4*)(pos + (size_t)rB * 256 + 4 * lane);
            float4 vA, vB;
            vA.x = eA.x + pA.x; vA.y = eA.y + pA.y; vA.z = eA.z + pA.z; vA.w = eA.w + pA.w;
            vB.x = eB.x + pB.x; vB.y = eB.y + pB.y; vB.z = eB.z + pB.z; vB.w = eB.w + pB.w;
            float sa = vA.x + vA.y + vA.z + vA.w;
            float qa = vA.x*vA.x + vA.y*vA.y + vA.z*vA.z + vA.w*vA.w;
            float d1a = vA.x*u4.x + vA.y*u4.y + vA.z*u4.z + vA.w*u4.w;
            float d2a = vA.x*t4.x + vA.y*t4.y + vA.z*t4.z + vA.w*t4.w;
            float sb = vB.x + vB.y + vB.z + vB.w;
            float qb = vB.x*vB.x + vB.y*vB.y + vB.z*vB.z + vB.w*vB.w;
            float d1b = vB.x*u4.x + vB.y*u4.y + vB.z*u4.z + vB.w*u4.w;
            float d2b = vB.x*t4.x + vB.y*t4.y + vB.z*t4.z + vB.w*t4.w;
            #pragma unroll
            for (int off = 32; off; off >>= 1) {   // one chain, ILP-8
                sa  += __shfl_xor(sa,  off);  sb  += __shfl_xor(sb,  off);
                qa  += __shfl_xor(qa,  off);  qb  += __shfl_xor(qb,  off);
                d1a += __shfl_xor(d1a, off);  d1b += __shfl_xor(d1b, off);
                d2a += __shfl_xor(d2a, off);  d2b += __shfl_xor(d2b, off);
            }
            float muA = sa * (1.0f/256.0f);
            float rsA = rsqrtf(qa * (1.0f/256.0f) - muA*muA + 1e-12f);
            float muB = sb * (1.0f/256.0f);
            float rsB = rsqrtf(qb * (1.0f/256.0f) - muB*muB + 1e-12f);
            float s1A = (rsA * (d1a - muA * cA) + cC) * L2E;   // pre-scaled
            float s2A = (rsA * (d2a - muA * cB) + cD) * L2E;
            float s1B = (rsB * (d1b - muB * cA) + cC) * L2E;
            float s2B = (rsB * (d2b - muB * cB) + cD) * L2E;
            if (lane == 0) {
                s1s[rA] = s1A; s2s[rA] = s2A;
                s1s[rB] = s1B; s2s[rB] = s2B;
            }
            rm = fmaxf(rm, fmaxf(s2A, s2B));
            uint2 oA, oB;
            oA.x = pk2((vA.x - muA) * rsA * g4.x + b4.x,
                       (vA.y - muA) * rsA * g4.y + b4.y);
            oA.y = pk2((vA.z - muA) * rsA * g4.z + b4.z,
                       (vA.w - muA) * rsA * g4.w + b4.w);
            oB.x = pk2((vB.x - muB) * rsB * g4.x + b4.x,
                       (vB.y - muB) * rsB * g4.y + b4.y);
            oB.y = pk2((vB.z - muB) * rsB * g4.z + b4.z,
                       (vB.w - muB) * rsB * g4.w + b4.w);
            int sl = (lane >> 1), sub = (lane & 1) * 4;
            *(uint2*)&xb[rA * 256 + ((sl ^ (rA & 7)) << 3) + sub] = oA;
            *(uint2*)&xb[rB * 256 + ((sl ^ (rB & 7)) << 3) + sub] = oB;
        }
        if (lane == 0) wmax[wid] = rm;
    }
    __syncthreads();   // bar1: xb(x), s1s, s2s, wmax ready

    // thread 0 folds the block s2max (published @bar2)
    if (tid == 0) {
        float m0 = wmax[0];
        #pragma unroll
        for (int k = 1; k < 16; ++k) m0 = fmaxf(m0, wmax[k]);
        s2r = m0;
    }

    if constexpr (P == 1) {   // consume Phase A outputs (anti-DCE), return
        float t = s1s[tid & 255] + s2s[(tid * 7 + 3) & 255];
        t += (float)xb[(tid * 131 + 7) & 65535];
        t += wmax[tid & 15];
        dummy[(size_t)b * 1024 + tid] = t;
        return;
    }

    // ---- GEMM1: h = x @ W; B-frags prefetched --------------------------
    f32x4 acc[4][4];
    #pragma unroll
    for (int mt = 0; mt < 4; ++mt)
        #pragma unroll
        for (int nt = 0; nt < 4; ++nt)
            acc[mt][nt] = (f32x4){0.f, 0.f, 0.f, 0.f};
    {
        short8 bf[4];
        #pragma unroll
        for (int nt = 0; nt < 4; ++nt)
            bf[nt] = *(const short8*)(wfrag
                       + ((size_t)(nw * 4 + nt) * 64 + lane) * 8);
        #pragma unroll
        for (int ks = 0; ks < 8; ++ks) {
            short8 bfn[4];
            if (ks < 7) {
                #pragma unroll
                for (int nt = 0; nt < 4; ++nt)
                    bfn[nt] = *(const short8*)(wfrag
                               + ((size_t)((ks + 1) * 16 + nw * 4 + nt) * 64 + lane) * 8);
            }
            #pragma unroll
            for (int mt = 0; mt < 4; ++mt) {
                int rl = iw_ * 64 + mt * 16 + li;
                short8 af = *(const short8*)&xb[rl * 256 + (((ks*4+g) ^ (rl & 7)) << 3)];
                #pragma unroll
                for (int nt = 0; nt < 4; ++nt)
                    acc[mt][nt] = __builtin_amdgcn_mfma_f32_16x16x32_bf16(
                        af, bf[nt], acc[mt][nt], 0, 0, 0);
            }
            if (ks < 7) {
                #pragma unroll
                for (int nt = 0; nt < 4; ++nt) bf[nt] = bfn[nt];
            }
        }
    }

    if constexpr (P == 2) {   // consume acc (anti-DCE), return
        float t = 0.f;
        #pragma unroll
        for (int mt = 0; mt < 4; ++mt)
            #pragma unroll
            for (int nt = 0; nt < 4; ++nt)
                t += acc[mt][nt][0] + acc[mt][nt][1] + acc[mt][nt][2] + acc[mt][nt][3];
        dummy[(size_t)b * 1024 + tid] = t;
        return;
    }

    __syncthreads();   // bar2: all x reads done; s2r published

    // ---- transpose h into xb as hT[c][j] ----------------------------------
    #pragma unroll
    for (int mt = 0; mt < 4; ++mt)
        #pragma unroll
        for (int nt = 0; nt < 4; ++nt) {
            int c  = nw * 64 + nt * 16 + li;
            int i0 = iw_ * 64 + mt * 16 + 4 * g;
            uint2 o;
            o.x = pk2(acc[mt][nt][0], acc[mt][nt][1]);
            o.y = pk2(acc[mt][nt][2], acc[mt][nt][3]);
            *(uint2*)&xb[c * 256 + (((i0 >> 3) ^ (c & 7)) << 3) + (i0 & 7)] = o;
        }
    __syncthreads();   // bar3: hT ready

    if constexpr (P == 3) {   // consume hT (anti-DCE), return
        uint2 v = *(const uint2*)&xb[((tid * 523) & 16383) * 4];
        dummy[(size_t)b * 1024 + tid] = (float)v.x + (float)v.y + s2r;
        return;
    }

    // ---- PV: out = (E @ h) * (1/l); wave grid 8 (i) x 2 (c) ---------------
    {
        float s2m = s2r;
        const int ig2 = wid >> 1;   // i-group: 32 rows
        const int ng2 = wid & 1;    // c-group: 128 cols
        f32x4 oacc[2][8];
        #pragma unroll
        for (int mt = 0; mt < 2; ++mt)
            #pragma unroll
            for (int nt = 0; nt < 8; ++nt)
                oacc[mt][nt] = (f32x4){0.f, 0.f, 0.f, 0.f};

        float aBase[2], bBase[2], pl[2];
        #pragma unroll
        for (int mt = 0; mt < 2; ++mt) {
            int i = ig2 * 32 + mt * 16 + li;
            float s1v = s1s[i];
            float mi  = lrelu(s1v + s2m);
            aBase[mt] = s1v - mi;
            bBase[mt] = fmaf(ALPHA, s1v, -mi);
            pl[mt] = 0.f;
        }

        #pragma unroll
        for (int js = 0; js < 8; ++js) {
            float4 sv0 = *(const float4*)&s2s[js * 32 + g * 8];
            float4 sv1 = *(const float4*)&s2s[js * 32 + g * 8 + 4];
            float s2l[8] = {sv0.x, sv0.y, sv0.z, sv0.w, sv1.x, sv1.y, sv1.z, sv1.w};

            short8 pfr[2];
            #pragma unroll
            for (int mt = 0; mt < 2; ++mt) {
                union { unsigned int u[4]; short8 s; } pk;
                #pragma unroll
                for (int q2 = 0; q2 < 4; ++q2) {
                    float sA = s2l[2 * q2], sB = s2l[2 * q2 + 1];
                    float p0 = __builtin_amdgcn_exp2f(
                        fmaxf(aBase[mt] + sA, fmaf(ALPHA, sA, bBase[mt])));
                    float p1 = __builtin_amdgcn_exp2f(
                        fmaxf(aBase[mt] + sB, fmaf(ALPHA, sB, bBase[mt])));
                    pl[mt] += p0 + p1;
                    pk.u[q2] = pk2(p0, p1);
                }
                pfr[mt] = pk.s;
            }
            #pragma unroll
            for (int nt = 0; nt < 8; ++nt) {
                int cl = ng2 * 128 + nt * 16 + li;
                short8 vf = *(const short8*)&xb[cl * 256
                              + (((js * 4 + g) ^ (cl & 7)) << 3)];
                #pragma unroll
                for (int mt = 0; mt < 2; ++mt)
                    oacc[mt][nt] = __builtin_amdgcn_mfma_f32_16x16x32_bf16(
                        pfr[mt], vf, oacc[mt][nt], 0, 0, 0);
            }
        }

        float linv[2][4];
        #pragma unroll
        for (int mt = 0; mt < 2; ++mt) {
            float t = pl[mt];
            t += __shfl_xor(t, 16);
            t += __shfl_xor(t, 32);
            #pragma unroll
            for (int q2 = 0; q2 < 4; ++q2)
                linv[mt][q2] = 1.0f / __shfl(t, 4 * g + q2);
        }

        size_t ob = (size_t)b * (256 * 256);
        #pragma unroll
        for (int mt = 0; mt < 2; ++mt)
            #pragma unroll
            for (int nt = 0; nt < 8; ++nt) {
                int c  = ng2 * 128 + nt * 16 + li;
                int i0 = ig2 * 32 + mt * 16 + 4 * g;
                #pragma unroll
                for (int q2 = 0; q2 < 4; ++q2)
                    out[ob + (size_t)(i0 + q2) * 256 + c] = oacc[mt][nt][q2] * linv[mt][q2];
            }
    }
}

extern "C" void kernel_launch(void* const* d_in, const int* in_sizes, int n_in,
                              void* d_out, int out_size, void* d_ws, size_t ws_size,
                              hipStream_t stream) {
    (void)in_sizes; (void)n_in; (void)out_size; (void)ws_size;
    const int*   seq   = (const int*)d_in[0];
    const float* emb   = (const float*)d_in[1];
    const float* pos   = (const float*)d_in[2];
    const float* W     = (const float*)d_in[3];
    const float* a1    = (const float*)d_in[4];
    const float* a2    = (const float*)d_in[5];
    const float* gamma = (const float*)d_in[6];
    const float* beta  = (const float*)d_in[7];

    char* ws = (char*)d_ws;
    u16*   wfrag = (u16*)ws;                     // 131072 B
    float* w1    = (float*)(ws + 131072);        // 1 KB
    float* w2    = (float*)(ws + 132096);        // 1 KB
    float* dummy = (float*)(ws + 262144);        // 1 MB keep-alive sink

    float* outp = (float*)d_out;
    hipLaunchKernelGGL(prep, dim3(68), dim3(256), 0, stream, W, a1, a2, wfrag, w1, w2);
    hipLaunchKernelGGL((gat<1>), dim3(256), dim3(1024), 0, stream,
                       seq, emb, pos, gamma, beta, w1, w2, wfrag, outp, dummy);
    hipLaunchKernelGGL((gat<2>), dim3(256), dim3(1024), 0, stream,
                       seq, emb, pos, gamma, beta, w1, w2, wfrag, outp, dummy);
    hipLaunchKernelGGL((gat<3>), dim3(256), dim3(1024), 0, stream,
                       seq, emb, pos, gamma, beta, w1, w2, wfrag, outp, dummy);
    hipLaunchKernelGGL((gat<4>), dim3(256), dim3(1024), 0, stream,
                       seq, emb, pos, gamma, beta, w1, w2, wfrag, outp, dummy);
}

// Round 16
// 72.569 us; speedup vs baseline: 1.9061x; 1.9061x over previous
//
#include <hip/hip_runtime.h>
#include <hip/hip_bf16.h>

#define ALPHA  0.2f
#define L2E    1.4426950408889634f

typedef __attribute__((ext_vector_type(8))) short  short8;
typedef __attribute__((ext_vector_type(4))) float  f32x4;
typedef unsigned short u16;

__device__ __forceinline__ u16 f2bf(float f) {
    union { __hip_bfloat16 h; u16 u; } v;
    v.h = __float2bfloat16(f);
    return v.u;
}
__device__ __forceinline__ unsigned pk2(float a, float b) {   // lo=a, hi=b
    union { __hip_bfloat162 h2; unsigned u; } v;
    float2 f2; f2.x = a; f2.y = b;
    v.h2 = __float22bfloat162_rn(f2);
    return v.u;
}
__device__ __forceinline__ float lrelu(float x) { return fmaxf(x, ALPHA * x); }

// ---- prep: W -> wfrag[pair 128][lane 64][8] (B-fragment-contiguous bf16),
//      pair = ks*16 + cblock; also w1 = W@a1, w2 = W@a2.
__global__ void prep(const float* __restrict__ W, const float* __restrict__ a1,
                     const float* __restrict__ a2, u16* __restrict__ wfrag,
                     float* __restrict__ w1, float* __restrict__ w2) {
    int b = blockIdx.x;
    if (b < 64) {
        int t    = threadIdx.x;
        int pair = b * 2 + (t >> 7);
        int l    = (t >> 1) & 63;
        int jh   = (t & 1) * 4;
        int ks   = pair >> 4, cb = pair & 15;
        int c  = cb * 16 + (l & 15);
        int k0 = ks * 32 + (l >> 4) * 8 + jh;
        ushort4 o;
        o.x = f2bf(W[(size_t)(k0 + 0) * 256 + c]);
        o.y = f2bf(W[(size_t)(k0 + 1) * 256 + c]);
        o.z = f2bf(W[(size_t)(k0 + 2) * 256 + c]);
        o.w = f2bf(W[(size_t)(k0 + 3) * 256 + c]);
        *(ushort4*)&wfrag[(size_t)pair * 512 + l * 8 + jh] = o;
    } else {
        int bb = b - 64;                       // 0..3
        int wv = threadIdx.x >> 6, lane = threadIdx.x & 63;
        for (int kk = 0; kk < 16; ++kk) {
            int k = bb * 64 + wv * 16 + kk;
            float4 wv4 = *(const float4*)(W + (size_t)k * 256 + 4 * lane);
            float4 a14 = *(const float4*)(a1 + 4 * lane);
            float4 a24 = *(const float4*)(a2 + 4 * lane);
            float d1 = wv4.x*a14.x + wv4.y*a14.y + wv4.z*a14.z + wv4.w*a14.w;
            float d2 = wv4.x*a24.x + wv4.y*a24.y + wv4.z*a24.z + wv4.w*a24.w;
            #pragma unroll
            for (int off = 32; off; off >>= 1) {
                d1 += __shfl_xor(d1, off);
                d2 += __shfl_xor(d2, off);
            }
            if (lane == 0) { w1[k] = d1; w2[k] = d2; }
        }
    }
}

// ======================= fused, row-split pipelined =========================
// grid 256, 1024 threads = 16 waves.
// A(rows 0-127) | bar1 | {prefetch upper e; G0 (i 0-127); A(rows 128-255)} |
// bar2 | G1 (i 128-255) | bar3 | transpose | bar4 | PV.
// Math identical to R12 (absmax 4.88e-4); only execution order differs.
__global__ __launch_bounds__(1024)
void gat(const int* __restrict__ item_seq, const float* __restrict__ emb,
         const float* __restrict__ pos, const float* __restrict__ gamma,
         const float* __restrict__ beta, const float* __restrict__ w1,
         const float* __restrict__ w2, const u16* __restrict__ wfrag,
         float* __restrict__ out)
{
    __shared__ u16 xb[256 * 256];            // 128 KB: x [r][k] then hT [c][j]
    __shared__ __align__(16) float s1s[256], s2s[256];
    __shared__ float wmax[16];
    const int b    = blockIdx.x;
    const int tid  = threadIdx.x;
    const int lane = tid & 63, wid = tid >> 6, g = lane >> 4, li = lane & 15;
    const int iw2  = wid >> 3, nw8 = wid & 7;  // G0/G1 wave grid: 2 i x 8 c

    // per-lane constants
    float4 g4  = *(const float4*)(gamma + 4 * lane);
    float4 b4  = *(const float4*)(beta  + 4 * lane);
    float4 w14 = *(const float4*)(w1    + 4 * lane);
    float4 w24 = *(const float4*)(w2    + 4 * lane);
    float4 u4, t4;
    u4.x = g4.x*w14.x; u4.y = g4.y*w14.y; u4.z = g4.z*w14.z; u4.w = g4.w*w14.w;
    t4.x = g4.x*w24.x; t4.y = g4.y*w24.y; t4.z = g4.z*w24.z; t4.w = g4.w*w24.w;
    float cA = u4.x + u4.y + u4.z + u4.w;
    float cB = t4.x + t4.y + t4.z + t4.w;
    float cC = b4.x*w14.x + b4.y*w14.y + b4.z*w14.z + b4.w*w14.w;
    float cD = b4.x*w24.x + b4.y*w24.y + b4.z*w24.z + b4.w*w24.w;
    #pragma unroll
    for (int off = 32; off; off >>= 1) {
        cA += __shfl_xor(cA, off); cB += __shfl_xor(cB, off);
        cC += __shfl_xor(cC, off); cD += __shfl_xor(cD, off);
    }

    // upper-half seq indices (independent; issue early)
    int gU[8];
    #pragma unroll
    for (int m = 0; m < 8; ++m) gU[m] = item_seq[b * 256 + 128 + m * 16 + wid];

    float rm = -3.0e38f;

    // ---- A0: rows 0..127 (wave-per-row, 2 rows per iter, R12 body) --------
    #pragma unroll 2
    for (int it = 0; it < 4; ++it) {
        int rA = it * 32 + wid, rB = rA + 16;
        int gA = item_seq[b * 256 + rA];
        int gB = item_seq[b * 256 + rB];
        float4 eA = *(const float4*)(emb + (size_t)gA * 256 + 4 * lane);
        float4 pA = *(const float4*)(pos + (size_t)rA * 256 + 4 * lane);
        float4 eB = *(const float4*)(emb + (size_t)gB * 256 + 4 * lane);
        float4 pB = *(const float4*)(pos + (size_t)rB * 256 + 4 * lane);
        float4 vA, vB;
        vA.x = eA.x + pA.x; vA.y = eA.y + pA.y; vA.z = eA.z + pA.z; vA.w = eA.w + pA.w;
        vB.x = eB.x + pB.x; vB.y = eB.y + pB.y; vB.z = eB.z + pB.z; vB.w = eB.w + pB.w;
        float sa = vA.x + vA.y + vA.z + vA.w;
        float qa = vA.x*vA.x + vA.y*vA.y + vA.z*vA.z + vA.w*vA.w;
        float d1a = vA.x*u4.x + vA.y*u4.y + vA.z*u4.z + vA.w*u4.w;
        float d2a = vA.x*t4.x + vA.y*t4.y + vA.z*t4.z + vA.w*t4.w;
        float sb = vB.x + vB.y + vB.z + vB.w;
        float qb = vB.x*vB.x + vB.y*vB.y + vB.z*vB.z + vB.w*vB.w;
        float d1b = vB.x*u4.x + vB.y*u4.y + vB.z*u4.z + vB.w*u4.w;
        float d2b = vB.x*t4.x + vB.y*t4.y + vB.z*t4.z + vB.w*t4.w;
        #pragma unroll
        for (int off = 32; off; off >>= 1) {
            sa  += __shfl_xor(sa,  off);  sb  += __shfl_xor(sb,  off);
            qa  += __shfl_xor(qa,  off);  qb  += __shfl_xor(qb,  off);
            d1a += __shfl_xor(d1a, off);  d1b += __shfl_xor(d1b, off);
            d2a += __shfl_xor(d2a, off);  d2b += __shfl_xor(d2b, off);
        }
        float muA = sa * (1.0f/256.0f);
        float rsA = rsqrtf(qa * (1.0f/256.0f) - muA*muA + 1e-12f);
        float muB = sb * (1.0f/256.0f);
        float rsB = rsqrtf(qb * (1.0f/256.0f) - muB*muB + 1e-12f);
        float s1A = (rsA * (d1a - muA * cA) + cC) * L2E;
        float s2A = (rsA * (d2a - muA * cB) + cD) * L2E;
        float s1B = (rsB * (d1b - muB * cA) + cC) * L2E;
        float s2B = (rsB * (d2b - muB * cB) + cD) * L2E;
        if (lane == 0) {
            s1s[rA] = s1A; s2s[rA] = s2A;
            s1s[rB] = s1B; s2s[rB] = s2B;
        }
        rm = fmaxf(rm, fmaxf(s2A, s2B));
        uint2 oA, oB;
        oA.x = pk2((vA.x - muA) * rsA * g4.x + b4.x,
                   (vA.y - muA) * rsA * g4.y + b4.y);
        oA.y = pk2((vA.z - muA) * rsA * g4.z + b4.z,
                   (vA.w - muA) * rsA * g4.w + b4.w);
        oB.x = pk2((vB.x - muB) * rsB * g4.x + b4.x,
                   (vB.y - muB) * rsB * g4.y + b4.y);
        oB.y = pk2((vB.z - muB) * rsB * g4.z + b4.z,
                   (vB.w - muB) * rsB * g4.w + b4.w);
        int sl = (lane >> 1), sub = (lane & 1) * 4;
        *(uint2*)&xb[rA * 256 + ((sl ^ (rA & 7)) << 3) + sub] = oA;
        *(uint2*)&xb[rB * 256 + ((sl ^ (rB & 7)) << 3) + sub] = oB;
    }
    __syncthreads();   // bar1: x rows 0..127 ready

    // prefetch upper-half e rows (land during G0)
    float4 eU[8];
    #pragma unroll
    for (int m = 0; m < 8; ++m)
        eU[m] = *(const float4*)(emb + (size_t)gU[m] * 256 + 4 * lane);

    // ---- G0: h rows 0..127 -------------------------------------------------
    f32x4 acc0[4][2];
    #pragma unroll
    for (int mt = 0; mt < 4; ++mt)
        #pragma unroll
        for (int nt = 0; nt < 2; ++nt)
            acc0[mt][nt] = (f32x4){0.f, 0.f, 0.f, 0.f};
    #pragma unroll
    for (int ks = 0; ks < 8; ++ks) {
        short8 bf[2];
        #pragma unroll
        for (int nt = 0; nt < 2; ++nt)
            bf[nt] = *(const short8*)(wfrag
                       + ((size_t)(ks * 16 + nw8 * 2 + nt) * 64 + lane) * 8);
        #pragma unroll
        for (int mt = 0; mt < 4; ++mt) {
            int rl = iw2 * 64 + mt * 16 + li;
            short8 af = *(const short8*)&xb[rl * 256 + (((ks*4+g) ^ (rl & 7)) << 3)];
            #pragma unroll
            for (int nt = 0; nt < 2; ++nt)
                acc0[mt][nt] = __builtin_amdgcn_mfma_f32_16x16x32_bf16(
                    af, bf[nt], acc0[mt][nt], 0, 0, 0);
        }
    }

    // ---- A1: rows 128..255 (e prefetched; p loaded now, L2-warm) ----------
    #pragma unroll 2
    for (int it = 0; it < 4; ++it) {
        int rA = 128 + it * 32 + wid, rB = rA + 16;
        float4 eA = eU[2 * it], eB = eU[2 * it + 1];
        float4 pA = *(const float4*)(pos + (size_t)rA * 256 + 4 * lane);
        float4 pB = *(const float4*)(pos + (size_t)rB * 256 + 4 * lane);
        float4 vA, vB;
        vA.x = eA.x + pA.x; vA.y = eA.y + pA.y; vA.z = eA.z + pA.z; vA.w = eA.w + pA.w;
        vB.x = eB.x + pB.x; vB.y = eB.y + pB.y; vB.z = eB.z + pB.z; vB.w = eB.w + pB.w;
        float sa = vA.x + vA.y + vA.z + vA.w;
        float qa = vA.x*vA.x + vA.y*vA.y + vA.z*vA.z + vA.w*vA.w;
        float d1a = vA.x*u4.x + vA.y*u4.y + vA.z*u4.z + vA.w*u4.w;
        float d2a = vA.x*t4.x + vA.y*t4.y + vA.z*t4.z + vA.w*t4.w;
        float sb = vB.x + vB.y + vB.z + vB.w;
        float qb = vB.x*vB.x + vB.y*vB.y + vB.z*vB.z + vB.w*vB.w;
        float d1b = vB.x*u4.x + vB.y*u4.y + vB.z*u4.z + vB.w*u4.w;
        float d2b = vB.x*t4.x + vB.y*t4.y + vB.z*t4.z + vB.w*t4.w;
        #pragma unroll
        for (int off = 32; off; off >>= 1) {
            sa  += __shfl_xor(sa,  off);  sb  += __shfl_xor(sb,  off);
            qa  += __shfl_xor(qa,  off);  qb  += __shfl_xor(qb,  off);
            d1a += __shfl_xor(d1a, off);  d1b += __shfl_xor(d1b, off);
            d2a += __shfl_xor(d2a, off);  d2b += __shfl_xor(d2b, off);
        }
        float muA = sa * (1.0f/256.0f);
        float rsA = rsqrtf(qa * (1.0f/256.0f) - muA*muA + 1e-12f);
        float muB = sb * (1.0f/256.0f);
        float rsB = rsqrtf(qb * (1.0f/256.0f) - muB*muB + 1e-12f);
        float s1A = (rsA * (d1a - muA * cA) + cC) * L2E;
        float s2A = (rsA * (d2a - muA * cB) + cD) * L2E;
        float s1B = (rsB * (d1b - muB * cA) + cC) * L2E;
        float s2B = (rsB * (d2b - muB * cB) + cD) * L2E;
        if (lane == 0) {
            s1s[rA] = s1A; s2s[rA] = s2A;
            s1s[rB] = s1B; s2s[rB] = s2B;
        }
        rm = fmaxf(rm, fmaxf(s2A, s2B));
        uint2 oA, oB;
        oA.x = pk2((vA.x - muA) * rsA * g4.x + b4.x,
                   (vA.y - muA) * rsA * g4.y + b4.y);
        oA.y = pk2((vA.z - muA) * rsA * g4.z + b4.z,
                   (vA.w - muA) * rsA * g4.w + b4.w);
        oB.x = pk2((vB.x - muB) * rsB * g4.x + b4.x,
                   (vB.y - muB) * rsB * g4.y + b4.y);
        oB.y = pk2((vB.z - muB) * rsB * g4.z + b4.z,
                   (vB.w - muB) * rsB * g4.w + b4.w);
        int sl = (lane >> 1), sub = (lane & 1) * 4;
        *(uint2*)&xb[rA * 256 + ((sl ^ (rA & 7)) << 3) + sub] = oA;
        *(uint2*)&xb[rB * 256 + ((sl ^ (rB & 7)) << 3) + sub] = oB;
    }
    if (lane == 0) wmax[wid] = rm;
    __syncthreads();   // bar2: x rows 128..255 + all stats ready

    // ---- G1: h rows 128..255 ----------------------------------------------
    f32x4 acc1[4][2];
    #pragma unroll
    for (int mt = 0; mt < 4; ++mt)
        #pragma unroll
        for (int nt = 0; nt < 2; ++nt)
            acc1[mt][nt] = (f32x4){0.f, 0.f, 0.f, 0.f};
    #pragma unroll
    for (int ks = 0; ks < 8; ++ks) {
        short8 bf[2];
        #pragma unroll
        for (int nt = 0; nt < 2; ++nt)
            bf[nt] = *(const short8*)(wfrag
                       + ((size_t)(ks * 16 + nw8 * 2 + nt) * 64 + lane) * 8);
        #pragma unroll
        for (int mt = 0; mt < 4; ++mt) {
            int rl = 128 + iw2 * 64 + mt * 16 + li;
            short8 af = *(const short8*)&xb[rl * 256 + (((ks*4+g) ^ (rl & 7)) << 3)];
            #pragma unroll
            for (int nt = 0; nt < 2; ++nt)
                acc1[mt][nt] = __builtin_amdgcn_mfma_f32_16x16x32_bf16(
                    af, bf[nt], acc1[mt][nt], 0, 0, 0);
        }
    }
    __syncthreads();   // bar3: all x reads done; safe to overwrite xb

    // ---- transpose both halves into xb as hT[c][j] -------------------------
    #pragma unroll
    for (int mt = 0; mt < 4; ++mt)
        #pragma unroll
        for (int nt = 0; nt < 2; ++nt) {
            int c  = nw8 * 32 + nt * 16 + li;
            int j0 = iw2 * 64 + mt * 16 + 4 * g;
            uint2 o0, o1;
            o0.x = pk2(acc0[mt][nt][0], acc0[mt][nt][1]);
            o0.y = pk2(acc0[mt][nt][2], acc0[mt][nt][3]);
            o1.x = pk2(acc1[mt][nt][0], acc1[mt][nt][1]);
            o1.y = pk2(acc1[mt][nt][2], acc1[mt][nt][3]);
            *(uint2*)&xb[c * 256 + (((j0 >> 3) ^ (c & 7)) << 3) + (j0 & 7)] = o0;
            int j1 = j0 + 128;
            *(uint2*)&xb[c * 256 + (((j1 >> 3) ^ (c & 7)) << 3) + (j1 & 7)] = o1;
        }
    __syncthreads();   // bar4: hT ready

    // ---- PV: out = (E @ h) * (1/l); wave grid 8 (i) x 2 (c) ---------------
    {
        float s2m = wmax[0];
        #pragma unroll
        for (int k = 1; k < 16; ++k) s2m = fmaxf(s2m, wmax[k]);

        const int ig2 = wid >> 1;   // i-group: 32 rows
        const int ng2 = wid & 1;    // c-group: 128 cols
        f32x4 oacc[2][8];
        #pragma unroll
        for (int mt = 0; mt < 2; ++mt)
            #pragma unroll
            for (int nt = 0; nt < 8; ++nt)
                oacc[mt][nt] = (f32x4){0.f, 0.f, 0.f, 0.f};

        float aBase[2], bBase[2], pl[2];
        #pragma unroll
        for (int mt = 0; mt < 2; ++mt) {
            int i = ig2 * 32 + mt * 16 + li;
            float s1v = s1s[i];
            float mi  = lrelu(s1v + s2m);
            aBase[mt] = s1v - mi;
            bBase[mt] = fmaf(ALPHA, s1v, -mi);
            pl[mt] = 0.f;
        }

        #pragma unroll
        for (int js = 0; js < 8; ++js) {
            float4 sv0 = *(const float4*)&s2s[js * 32 + g * 8];
            float4 sv1 = *(const float4*)&s2s[js * 32 + g * 8 + 4];
            float s2l[8] = {sv0.x, sv0.y, sv0.z, sv0.w, sv1.x, sv1.y, sv1.z, sv1.w};

            short8 pfr[2];
            #pragma unroll
            for (int mt = 0; mt < 2; ++mt) {
                union { unsigned int u[4]; short8 s; } pk;
                #pragma unroll
                for (int q2 = 0; q2 < 4; ++q2) {
                    float sA = s2l[2 * q2], sB = s2l[2 * q2 + 1];
                    float p0 = __builtin_amdgcn_exp2f(
                        fmaxf(aBase[mt] + sA, fmaf(ALPHA, sA, bBase[mt])));
                    float p1 = __builtin_amdgcn_exp2f(
                        fmaxf(aBase[mt] + sB, fmaf(ALPHA, sB, bBase[mt])));
                    pl[mt] += p0 + p1;
                    pk.u[q2] = pk2(p0, p1);
                }
                pfr[mt] = pk.s;
            }
            #pragma unroll
            for (int nt = 0; nt < 8; ++nt) {
                int cl = ng2 * 128 + nt * 16 + li;
                short8 vf = *(const short8*)&xb[cl * 256
                              + (((js * 4 + g) ^ (cl & 7)) << 3)];
                #pragma unroll
                for (int mt = 0; mt < 2; ++mt)
                    oacc[mt][nt] = __builtin_amdgcn_mfma_f32_16x16x32_bf16(
                        pfr[mt], vf, oacc[mt][nt], 0, 0, 0);
            }
        }

        float linv[2][4];
        #pragma unroll
        for (int mt = 0; mt < 2; ++mt) {
            float t = pl[mt];
            t += __shfl_xor(t, 16);
            t += __shfl_xor(t, 32);
            #pragma unroll
            for (int q2 = 0; q2 < 4; ++q2)
                linv[mt][q2] = 1.0f / __shfl(t, 4 * g + q2);
        }

        size_t ob = (size_t)b * (256 * 256);
        #pragma unroll
        for (int mt = 0; mt < 2; ++mt)
            #pragma unroll
            for (int nt = 0; nt < 8; ++nt) {
                int c  = ng2 * 128 + nt * 16 + li;
                int i0 = ig2 * 32 + mt * 16 + 4 * g;
                #pragma unroll
                for (int q2 = 0; q2 < 4; ++q2)
                    out[ob + (size_t)(i0 + q2) * 256 + c] = oacc[mt][nt][q2] * linv[mt][q2];
            }
    }
}

extern "C" void kernel_launch(void* const* d_in, const int* in_sizes, int n_in,
                              void* d_out, int out_size, void* d_ws, size_t ws_size,
                              hipStream_t stream) {
    (void)in_sizes; (void)n_in; (void)out_size; (void)ws_size;
    const int*   seq   = (const int*)d_in[0];
    const float* emb   = (const float*)d_in[1];
    const float* pos   = (const float*)d_in[2];
    const float* W     = (const float*)d_in[3];
    const float* a1    = (const float*)d_in[4];
    const float* a2    = (const float*)d_in[5];
    const float* gamma = (const float*)d_in[6];
    const float* beta  = (const float*)d_in[7];

    char* ws = (char*)d_ws;
    u16*   wfrag = (u16*)ws;                     // 131072 B
    float* w1    = (float*)(ws + 131072);        // 1 KB
    float* w2    = (float*)(ws + 132096);        // 1 KB

    hipLaunchKernelGGL(prep, dim3(68), dim3(256), 0, stream, W, a1, a2, wfrag, w1, w2);
    hipLaunchKernelGGL(gat, dim3(256), dim3(1024), 0, stream,
                       seq, emb, pos, gamma, beta, w1, w2, wfrag, (float*)d_out);
}